// Round 4
// baseline (2835.025 us; speedup 1.0000x reference)
//
#include <hip/hip_runtime.h>
#include <hip/hip_bf16.h>

// LightGCN propagation: ego = concat(user,item); 3x { ego = A@ego; acc += ego }; out = acc/4
// Round-4: round-2-PROVEN pipeline (per-row CSR + per-row wave SpMM + init/final),
// with k_scatter's 16x write amplification fixed by a two-stage scatter:
//   stage 1: edge partition into 64-row buckets (packed u64, 8 index-derived
//            cursor shards; cursor ws ~150KB -> L2-merged writes)
//   stage 2: per-bucket in-place CSR ordering via LDS staging (dest window ~21KB)

typedef unsigned short u16;
typedef unsigned int   u32;
typedef unsigned long long u64;

#define USER_ELEMS   (200000 * 64)
#define N_NODES      300000
#define EMB          64
#define NNZ          12800000
#define TOTAL_ELEMS  (N_NODES * EMB)        // 19,200,000
#define SCAN_CHUNK   2048
#define SCAN_NB      147                    // ceil(300000/2048)

#define NB           4688                   // 64-row buckets
#define NSH          8                      // cursor shards (edge-index-derived)
#define BCAP         6144                   // LDS bucket capacity (mean 2731, sigma 52)

// workspace sizes (bytes)
#define FLAGS_SZ   256ULL
#define ACC_SZ     76800000ULL
#define EGO_SZ     38400000ULL
#define EDGES_SZ   102400000ULL             // NNZ * 8
#define RP_SZ      1200128ULL               // 300,032 ints
#define BS_SZ      1024ULL
#define H8_SZ      (8ULL * NB * 4ULL)       // 150,016
#define MAIN_NEED  (FLAGS_SZ + ACC_SZ + EGO_SZ + EDGES_SZ + 2*RP_SZ + 2*BS_SZ + 2*H8_SZ) // 220,302,592
#define LAYER_SZ   76800000ULL              // T3 fallback

__device__ __forceinline__ float bf2f(u16 b) {
    return __uint_as_float(((u32)b) << 16);
}
__device__ __forceinline__ u16 f2bf(float f) {
    u32 u = __float_as_uint(f);
    u32 r = (u + 0x7fffu + ((u >> 16) & 1u)) >> 16;   // RNE
    return (u16)r;
}

// ---------------- dtype detection (PROVEN r2) ----------------
__global__ void k_detect(const u16* __restrict__ emb, const u16* __restrict__ vals,
                         int* __restrict__ flags) {
    int lane = threadIdx.x;
    u16 a = emb[lane * 2];
    int ea = (a >> 7) & 0xFF;
    bool pa = (ea >= 0x60 && ea <= 0x7E);
    unsigned long long ba = __ballot(pa);
    u16 b = vals[lane * 2];
    int eb = (b >> 7) & 0xFF;
    bool pb = (eb >= 0x60 && eb <= 0x7E);
    unsigned long long bb = __ballot(pb);
    if (lane == 0) {
        flags[0] = (__popcll(ba) >= 56) ? 0 : 1;   // 0 = bf16, 1 = fp32
        flags[1] = (__popcll(bb) >= 56) ? 0 : 1;
    }
}

// ---------------- init: ego0 bf16 + acc fp32 (PROVEN r2) ----------------
__global__ void k_init(const void* __restrict__ user, const void* __restrict__ item,
                       const int* __restrict__ flags,
                       u16* __restrict__ ego, float* __restrict__ acc, int write_acc) {
    int t = blockIdx.x * blockDim.x + threadIdx.x;
    int e = t * 4;
    if (e >= TOTAL_ELEMS) return;
    float4 f;
    if (flags[0]) {
        const float* src = (e < USER_ELEMS) ? ((const float*)user + e)
                                            : ((const float*)item + (e - USER_ELEMS));
        f = *(const float4*)src;
    } else {
        const u16* src = (e < USER_ELEMS) ? ((const u16*)user + e)
                                          : ((const u16*)item + (e - USER_ELEMS));
        ushort4 v = *(const ushort4*)src;
        f.x = bf2f(v.x); f.y = bf2f(v.y); f.z = bf2f(v.z); f.w = bf2f(v.w);
    }
    ushort4 o;
    o.x = f2bf(f.x); o.y = f2bf(f.y); o.z = f2bf(f.z); o.w = f2bf(f.w);
    *(ushort4*)(ego + e) = o;
    if (write_acc) *(float4*)(acc + e) = f;
}

// ---------------- per-row histogram (PROVEN r2) ----------------
__global__ void k_hist_rows(const int* __restrict__ rows, int* __restrict__ cnt) {
    int e = blockIdx.x * blockDim.x + threadIdx.x;
    if (e < NNZ) atomicAdd(&cnt[rows[e]], 1);
}

// ---------------- row scan phase 1 (PROVEN r2) ----------------
__global__ void k_scan_reduce(const int* __restrict__ cnt, int* __restrict__ blockSums) {
    __shared__ int s[256];
    int b = blockIdx.x;
    int base = b * SCAN_CHUNK + threadIdx.x;
    int sum = 0;
#pragma unroll
    for (int k = 0; k < 8; ++k) {
        int i = base + k * 256;
        if (i < N_NODES) sum += cnt[i];
    }
    s[threadIdx.x] = sum;
    __syncthreads();
    for (int off = 128; off > 0; off >>= 1) {
        if (threadIdx.x < (unsigned)off) s[threadIdx.x] += s[threadIdx.x + off];
        __syncthreads();
    }
    if (threadIdx.x == 0) blockSums[b] = s[0];
}

// ---------------- row scan phase 2 (PROVEN r2) ----------------
__global__ void k_scan_block(const int* __restrict__ blockSums, int* __restrict__ blockOffs) {
    __shared__ int s[256];
    int x = (threadIdx.x < SCAN_NB) ? blockSums[threadIdx.x] : 0;
    s[threadIdx.x] = x;
    __syncthreads();
    for (int off = 1; off < 256; off <<= 1) {
        int t = 0;
        if (threadIdx.x >= (unsigned)off) t = s[threadIdx.x - off];
        __syncthreads();
        s[threadIdx.x] += t;
        __syncthreads();
    }
    if (threadIdx.x < SCAN_NB) blockOffs[threadIdx.x] = s[threadIdx.x] - x;
}

// ---------------- row scan phase 3 -> row_ptr (PROVEN r2, cursor writes removed) ----------------
__global__ void k_scan_down(const int* __restrict__ cnt, const int* __restrict__ blockOffs,
                            int* __restrict__ row_ptr) {
    __shared__ int s[256];
    int b = blockIdx.x;
    int base = b * SCAN_CHUNK + threadIdx.x * 8;
    int v[8];
    int tsum = 0;
#pragma unroll
    for (int k = 0; k < 8; ++k) {
        int i = base + k;
        v[k] = (i < N_NODES) ? cnt[i] : 0;
        tsum += v[k];
    }
    s[threadIdx.x] = tsum;
    __syncthreads();
    for (int off = 1; off < 256; off <<= 1) {
        int t = 0;
        if (threadIdx.x >= (unsigned)off) t = s[threadIdx.x - off];
        __syncthreads();
        s[threadIdx.x] += t;
        __syncthreads();
    }
    int running = blockOffs[b] + (s[threadIdx.x] - tsum);
#pragma unroll
    for (int k = 0; k < 8; ++k) {
        int i = base + k;
        if (i < N_NODES) row_ptr[i] = running;
        running += v[k];
    }
    if (b == 0 && threadIdx.x == 0) row_ptr[N_NODES] = NNZ;
}

// ---------------- bucket-shard histogram (shard = edge-index derived) ----------------
__global__ void k_hist8(const int* __restrict__ rows, u32* __restrict__ hist8) {
    int e = blockIdx.x * blockDim.x + threadIdx.x;
    if (e >= NNZ) return;
    int sh = (e >> 11) & (NSH - 1);
    atomicAdd(&hist8[sh * NB + (rows[e] >> 6)], 1u);
}

// ---------------- derive shard cursors from row_ptr + hist8 ----------------
__global__ void k_mkcur(const int* __restrict__ row_ptr, const u32* __restrict__ hist8,
                        u32* __restrict__ cursor) {
    int b = blockIdx.x * blockDim.x + threadIdx.x;
    if (b >= NB) return;
    u32 running = (u32)row_ptr[b << 6];     // bucket base == CSR base of row 64b
#pragma unroll
    for (int s = 0; s < NSH; ++s) {
        cursor[s * NB + b] = running;
        running += hist8[s * NB + b];
    }
}

// ---------------- stage-1 partition: edges -> bucket-grouped packed u64 ----------------
// pack: val_bf16[63:48] | rowloc6[24:19] | col19[18:0]
__global__ void k_partition(const int* __restrict__ rows, const int* __restrict__ cols,
                            const void* __restrict__ vals, const int* __restrict__ flags,
                            u32* __restrict__ cursor, u64* __restrict__ edges) {
    int e = blockIdx.x * blockDim.x + threadIdx.x;
    if (e >= NNZ) return;
    int r = rows[e];
    int c = cols[e];
    u16 w = flags[1] ? f2bf(((const float*)vals)[e]) : ((const u16*)vals)[e];
    int sh = (e >> 11) & (NSH - 1);
    u32 p = atomicAdd(&cursor[sh * NB + (r >> 6)], 1u);
    edges[p] = ((u64)w << 48) | ((u64)(r & 63) << 19) | (u64)(u32)c;
}

// ---------------- stage-2: per-bucket in-place CSR ordering via LDS ----------------
// Bucket b's range [row_ptr[64b], row_ptr[64(b+1)]) is loaded fully into LDS
// (cap 6144 = mean+65sigma), then scattered to exact per-row CSR slots.
__global__ void __launch_bounds__(256) k_bsort(const int* __restrict__ row_ptr,
                                               u64* edges) {
    __shared__ u64 buf[BCAP];       // 48 KB
    __shared__ u32 lcur[64];
    int b = blockIdx.x;
    int start = row_ptr[b << 6];
    int rend_idx = (b + 1) << 6; if (rend_idx > N_NODES) rend_idx = N_NODES;
    int end = row_ptr[rend_idx];
    int cnt = end - start;
    if (cnt > BCAP) cnt = BCAP;     // statistically impossible (+65 sigma); safety clamp
    if (threadIdx.x < 64) lcur[threadIdx.x] = 0;
    for (int j = threadIdx.x; j < cnt; j += 256) buf[j] = edges[start + j];
    __syncthreads();
    int rbase = b << 6;
    for (int j = threadIdx.x; j < cnt; j += 256) {
        u64 E = buf[j];
        int rl = (int)((E >> 19) & 63);
        u32 rk = atomicAdd(&lcur[rl], 1u);
        edges[row_ptr[rbase + rl] + rk] = E;
    }
}

// ---------------- SpMM (PROVEN r2 structure): one wave/row, lane = dim ----------------
__global__ void __launch_bounds__(256) k_spmm(
    const int* __restrict__ row_ptr, const u64* __restrict__ edges,
    const u16* __restrict__ ego_in, u16* __restrict__ ego_out,
    float* __restrict__ acc) {
    int row = __builtin_amdgcn_readfirstlane(
        (int)((blockIdx.x * blockDim.x + threadIdx.x) >> 6));
    int lane = threadIdx.x & 63;
    if (row >= N_NODES) return;
    int start = row_ptr[row];
    int end   = row_ptr[row + 1];
    float a = 0.f;
    int j = start;
    for (; j + 8 <= end; j += 8) {          // 8-deep MLP
        u64 E[8];
#pragma unroll
        for (int k = 0; k < 8; ++k) E[k] = edges[j + k];
        float X[8];
#pragma unroll
        for (int k = 0; k < 8; ++k) {
            int c = (int)(E[k] & 0x7FFFF);
            X[k] = bf2f(ego_in[(c << 6) + lane]);
        }
#pragma unroll
        for (int k = 0; k < 8; ++k) {
            a += bf2f((u16)(E[k] >> 48)) * X[k];
        }
    }
    for (; j < end; ++j) {
        u64 E = edges[j];
        int c = (int)(E & 0x7FFFF);
        a += bf2f((u16)(E >> 48)) * bf2f(ego_in[(c << 6) + lane]);
    }
    int o = row * EMB + lane;
    acc[o] += a;
    ego_out[o] = f2bf(a);
}

// ---------------- finalize (PROVEN r2) ----------------
__global__ void k_final(const float* __restrict__ acc, const int* __restrict__ flags,
                        void* __restrict__ out) {
    int t = blockIdx.x * blockDim.x + threadIdx.x;
    int e = t * 4;
    if (e >= TOTAL_ELEMS) return;
    float4 f = *(const float4*)(acc + e);
    f.x *= 0.25f; f.y *= 0.25f; f.z *= 0.25f; f.w *= 0.25f;
    if (flags[0]) {
        *(float4*)((float*)out + e) = f;
    } else {
        ushort4 v;
        v.x = f2bf(f.x); v.y = f2bf(f.y); v.z = f2bf(f.z); v.w = f2bf(f.w);
        *(ushort4*)((u16*)out + e) = v;
    }
}

// ---------------- T3 fallback (PROVEN-correct structure) ----------------
__global__ void __launch_bounds__(256) k_edge_atomic(
    const int* __restrict__ rows, const int* __restrict__ cols,
    const void* __restrict__ vals, const int* __restrict__ flags,
    const u16* __restrict__ ego, float* __restrict__ layer) {
    long long t = (long long)blockIdx.x * blockDim.x + threadIdx.x;
    long long e = t >> 4;
    if (e >= NNZ) return;
    int d4 = (int)(t & 15) * 4;
    int r = rows[e], c = cols[e];
    float w = flags[1] ? ((const float*)vals)[e] : bf2f(((const u16*)vals)[e]);
    ushort4 x = *(const ushort4*)(ego + c * EMB + d4);
    float* dst = layer + (long long)r * EMB + d4;
    atomicAdd(dst + 0, w * bf2f(x.x));
    atomicAdd(dst + 1, w * bf2f(x.y));
    atomicAdd(dst + 2, w * bf2f(x.z));
    atomicAdd(dst + 3, w * bf2f(x.w));
}

__global__ void k_layer_fin(float* __restrict__ layer, float* __restrict__ acc,
                            u16* __restrict__ ego) {
    int t = blockIdx.x * blockDim.x + threadIdx.x;
    int e = t * 4;
    if (e >= TOTAL_ELEMS) return;
    float4 L = *(const float4*)(layer + e);
    float4 A = *(const float4*)(acc + e);
    A.x += L.x; A.y += L.y; A.z += L.z; A.w += L.w;
    *(float4*)(acc + e) = A;
    ushort4 o;
    o.x = f2bf(L.x); o.y = f2bf(L.y); o.z = f2bf(L.z); o.w = f2bf(L.w);
    *(ushort4*)(ego + e) = o;
    *(float4*)(layer + e) = float4{0.f, 0.f, 0.f, 0.f};
}

extern "C" void kernel_launch(void* const* d_in, const int* in_sizes, int n_in,
                              void* d_out, int out_size, void* d_ws, size_t ws_size,
                              hipStream_t stream) {
    const void* user = d_in[0];
    const void* item = d_in[1];
    const void* vals = d_in[2];
    const int*  rows = (const int*)d_in[3];
    const int*  cols = (const int*)d_in[4];

    char* ws = (char*)d_ws;
    int*   flags = (int*)ws;
    size_t off = FLAGS_SZ;
    float* acc = (float*)(ws + off); off += ACC_SZ;

    const int initGrid = (TOTAL_ELEMS / 4 + 255) / 256;   // 18750
    const int edgeGrid = (NNZ + 255) / 256;               // 50000
    const int spmmGrid = (N_NODES * 64) / 256;            // 75000

    k_detect<<<1, 64, 0, stream>>>((const u16*)user, (const u16*)vals, flags);

    if (ws_size >= MAIN_NEED) {
        u16* ego0    = (u16*)(ws + off); off += EGO_SZ;
        u64* edges   = (u64*)(ws + off); off += EDGES_SZ;
        int* rowcnt  = (int*)(ws + off); off += RP_SZ;
        int* row_ptr = (int*)(ws + off); off += RP_SZ;
        int* bsums   = (int*)(ws + off); off += BS_SZ;
        int* boffs   = (int*)(ws + off); off += BS_SZ;
        u32* hist8   = (u32*)(ws + off); off += H8_SZ;
        u32* cursor  = (u32*)(ws + off); off += H8_SZ;
        u16* ego1    = (u16*)d_out;      // ping-pong; k_final overwrites d_out last

        hipMemsetAsync(rowcnt, 0, RP_SZ, stream);
        hipMemsetAsync(hist8, 0, H8_SZ, stream);

        k_init<<<initGrid, 256, 0, stream>>>(user, item, flags, ego0, acc, 1);
        k_hist_rows<<<edgeGrid, 256, 0, stream>>>(rows, rowcnt);
        k_scan_reduce<<<SCAN_NB, 256, 0, stream>>>(rowcnt, bsums);
        k_scan_block<<<1, 256, 0, stream>>>(bsums, boffs);
        k_scan_down<<<SCAN_NB, 256, 0, stream>>>(rowcnt, boffs, row_ptr);
        k_hist8<<<edgeGrid, 256, 0, stream>>>(rows, hist8);
        k_mkcur<<<(NB + 255) / 256, 256, 0, stream>>>(row_ptr, hist8, cursor);
        k_partition<<<edgeGrid, 256, 0, stream>>>(rows, cols, vals, flags, cursor, edges);
        k_bsort<<<NB, 256, 0, stream>>>(row_ptr, edges);

        k_spmm<<<spmmGrid, 256, 0, stream>>>(row_ptr, edges, ego0, ego1, acc);
        k_spmm<<<spmmGrid, 256, 0, stream>>>(row_ptr, edges, ego1, ego0, acc);
        k_spmm<<<spmmGrid, 256, 0, stream>>>(row_ptr, edges, ego0, ego1, acc);

        k_final<<<initGrid, 256, 0, stream>>>(acc, flags, d_out);
    } else {
        float* layer = (float*)(ws + off); off += LAYER_SZ;
        u16* ego = (u16*)d_out;
        hipMemsetAsync(layer, 0, LAYER_SZ, stream);
        k_init<<<initGrid, 256, 0, stream>>>(user, item, flags, ego, acc, 1);
        const long long atomThreads = (long long)NNZ * 16;
        const int atomGrid = (int)((atomThreads + 255) / 256);
        for (int l = 0; l < 3; ++l) {
            k_edge_atomic<<<atomGrid, 256, 0, stream>>>(rows, cols, vals, flags, ego, layer);
            k_layer_fin<<<initGrid, 256, 0, stream>>>(layer, acc, ego);
        }
        k_final<<<initGrid, 256, 0, stream>>>(acc, flags, d_out);
    }
}